// Round 5
// baseline (771.030 us; speedup 1.0000x reference)
//
#include <hip/hip_runtime.h>

typedef unsigned short u16;
typedef __attribute__((ext_vector_type(8))) short short8;
typedef __attribute__((ext_vector_type(4))) float f32x4;

#define BATCH 256
#define S_LEN 100
#define EMB   1024
#define NHEAD 16
#define HDIM  64

__device__ __forceinline__ float b2f(u16 h) {
  union { unsigned u; float f; } v; v.u = ((unsigned)h) << 16; return v.f;
}
__device__ __forceinline__ u16 f2bf(float f) {
  union { float f; unsigned u; } v; v.f = f;
  unsigned r = v.u + 0x7fffu + ((v.u >> 16) & 1u);
  return (u16)(r >> 16);
}

__device__ __forceinline__ void gld_lds16(const u16* g, u16* l) {
  __builtin_amdgcn_global_load_lds((const __attribute__((address_space(1))) void*)g,
                                   (__attribute__((address_space(3))) void*)l,
                                   16, 0, 0);
}

#define MFMA16(a, b, c) __builtin_amdgcn_mfma_f32_16x16x32_bf16(a, b, c, 0, 0, 0)

// ---------------------------------------------------------------------------
// Weight transpose+cast: W[k][n] (1024x1024 f32) -> Wt[n][k] bf16. grid(16,16,4)
// ---------------------------------------------------------------------------
__global__ __launch_bounds__(256) void w_xpose(
    const float* __restrict__ Wq, const float* __restrict__ Wk,
    const float* __restrict__ Wv, const float* __restrict__ Wo,
    u16* __restrict__ WtQ, u16* __restrict__ WtK,
    u16* __restrict__ WtV, u16* __restrict__ WtO)
{
  __shared__ u16 tile[64 * 73];
  int z = blockIdx.z;
  const float* W = (z == 0) ? Wq : (z == 1) ? Wk : (z == 2) ? Wv : Wo;
  u16* Wt        = (z == 0) ? WtQ : (z == 1) ? WtK : (z == 2) ? WtV : WtO;
  int k0 = blockIdx.x * 64, n0 = blockIdx.y * 64;
  for (int idx = threadIdx.x; idx < 4096; idx += 256) {
    int r = idx >> 6, c = idx & 63;
    tile[r * 73 + c] = f2bf(W[(size_t)(k0 + r) * EMB + n0 + c]);
  }
  __syncthreads();
  for (int idx = threadIdx.x; idx < 4096; idx += 256) {
    int c = idx >> 6, r = idx & 63;
    Wt[(size_t)(n0 + c) * EMB + k0 + r] = tile[r * 73 + c];
  }
}

// ---------------------------------------------------------------------------
// x [B][E][S] f32 -> xT [B][S][E] bf16, adding pos_encoding[s][e]. grid(16,B)
// ---------------------------------------------------------------------------
__global__ __launch_bounds__(256) void xpose_pos(
    const float* __restrict__ x, const float* __restrict__ pos, u16* __restrict__ xT)
{
  __shared__ float tile[64 * 105];
  int e0 = blockIdx.x * 64;
  int b  = blockIdx.y;
  const float* xb = x + (size_t)b * EMB * S_LEN;
  for (int idx = threadIdx.x; idx < 6400; idx += 256) {
    int i = idx / 100, s = idx - i * 100;
    tile[i * 105 + s] = xb[(size_t)(e0 + i) * S_LEN + s];
  }
  __syncthreads();
  for (int idx = threadIdx.x; idx < 6400; idx += 256) {
    int s = idx >> 6, i = idx & 63;
    float v = tile[i * 105 + s] + pos[(size_t)s * EMB + e0 + i];
    xT[(size_t)b * (S_LEN * EMB) + (size_t)s * EMB + e0 + i] = f2bf(v);
  }
}

// ---------------------------------------------------------------------------
// tmp [B][S][E] bf16 -> out [B][E][S] f32.  grid (16, B)
// ---------------------------------------------------------------------------
__global__ __launch_bounds__(256) void out_xpose(
    const u16* __restrict__ tmp, float* __restrict__ out)
{
  __shared__ u16 tile[100 * 73];
  int e0 = blockIdx.x * 64;
  int b  = blockIdx.y;
  for (int idx = threadIdx.x; idx < 6400; idx += 256) {
    int s = idx >> 6, i = idx & 63;
    tile[s * 73 + i] = tmp[(size_t)b * (S_LEN * EMB) + (size_t)s * EMB + e0 + i];
  }
  __syncthreads();
  for (int idx = threadIdx.x; idx < 6400; idx += 256) {
    int i = idx / 100, s = idx - i * 100;
    out[((size_t)b * EMB + e0 + i) * S_LEN + s] = b2f(tile[s * 73 + i]);
  }
}

// ---------------------------------------------------------------------------
// GEMM 256x256, deep-ring pipeline (round 5).
//
// Diagnosis R4: 1 block/CU + 4 barriers/tile + <=1-tile prefetch exposed
// ~2000cy loaded-latency at every gate -> 10 B/cyc/CU delivery (m97-style
// multi-block kernels sustain 22+). Fix: deepen prefetch to 1.5-2 tiles and
// cut sync to ONE (vmcnt+barrier) per K-tile so waves de-sync inside the
// tile body and cross-cover latency.
//
// Geometry: 512 thr = 8 waves (2M x 4N), wave C = 128x64, BK=64.
// LDS: ring of FIVE 32 KB slots = 160 KB (the full CU budget; attn kernel is
// a separate dispatch). Slot s=(tile t=s>>1, half h=s&1) holds
// A[128 rows of m-half h][64k] + B[128 rows of n-half h][64k], XOR-swizzled
// (verified 0-conflict layout), linear DMA dest (4 gld_lds16/thread/slot).
//
// Schedule (per-wave vmcnt counts its own 4 loads/slot):
//   prologue: issue s0..s4 (20 loads)
//   tile 0:  vmcnt(12) [forces s0,s1]; barrier; body
//   tile t (1..14): vmcnt(4) [outstanding s2t..s2t+2 = 12, forces s2t,s2t+1];
//                   barrier; issue s=2t+3,2t+4 (while s<=31); body
//   tile 15: vmcnt(0); barrier; body
// Slack: odd slots ~1 tile, even slots ~2 tiles (avg 1.5 = m201 depth).
// In-flight: 12 loads/wave = 96 KB/CU (2.7x R4). WAR: slot s+5 overwrites a
// slot whose reads finished one full tile before the tile-top barrier.
// ---------------------------------------------------------------------------
__global__ __launch_bounds__(512) void gemm256(
    const u16* __restrict__ A,
    const u16* __restrict__ Bt0, const u16* __restrict__ Bt1, const u16* __restrict__ Bt2,
    const float* __restrict__ bias0, const float* __restrict__ bias1, const float* __restrict__ bias2,
    u16* __restrict__ C0, u16* __restrict__ C1, u16* __restrict__ C2)
{
  __shared__ u16 lds[5 * 16384];   // 5 slots x 32 KB = 160 KB

  const int z = blockIdx.z;
  const u16* Bt     = (z == 0) ? Bt0 : (z == 1) ? Bt1 : Bt2;
  const float* bias = (z == 0) ? bias0 : (z == 1) ? bias1 : bias2;
  u16* C            = (z == 0) ? C0 : (z == 1) ? C1 : C2;

  const int tid  = threadIdx.x;
  const int wave = tid >> 6, lane = tid & 63;
  const int quad = lane >> 4, l16 = lane & 15;
  const int m0 = blockIdx.x * 256, n0 = blockIdx.y * 256;
  const int WM = (wave >> 2) * 128, WN = (wave & 3) * 64;

  // staging constants: dest row = tid>>3 within each 64-row unit, chunk = tid&7,
  // source chunk pre-swizzled so reads use chunk^(row&7).
  const int rq64 = tid >> 3;                       // 0..63
  const int jg   = ((tid & 7) ^ (rq64 & 7)) << 3;  // swizzled source chunk (u16)

  // fragment-read constants
  const int swz = l16 & 7;
  const int cA  = (quad ^ swz) << 3;        // kh=0 chunk
  const int cB  = ((quad + 4) ^ swz) << 3;  // kh=1 chunk
  const int wmh = WM >> 7;                  // A slot parity for this wave
  const int wnh = WN >> 7;                  // B slot parity
  const int bRow = (WN & 127) + l16;

  // issue one 32KB slot: 4 x gld_lds16 per thread (A-lo, A-hi, B-lo, B-hi)
#define STAGE_SLOT(s, ri) { \
    const size_t kof = (size_t)((s) >> 1) * 64 + jg; \
    const int hof = 128 * ((s) & 1); \
    u16* dst = lds + (size_t)(ri) * 16384 + tid * 8; \
    gld_lds16(A  + (size_t)(m0 + hof + rq64)      * EMB + kof, dst); \
    gld_lds16(A  + (size_t)(m0 + hof + 64 + rq64) * EMB + kof, dst + 4096); \
    gld_lds16(Bt + (size_t)(n0 + hof + rq64)      * EMB + kof, dst + 8192); \
    gld_lds16(Bt + (size_t)(n0 + hof + 64 + rq64) * EMB + kof, dst + 12288); \
  }

  f32x4 acc[8][4] = {};

  // prologue: 5 slots in flight
  STAGE_SLOT(0, 0); STAGE_SLOT(1, 1); STAGE_SLOT(2, 2);
  STAGE_SLOT(3, 3); STAGE_SLOT(4, 4);

  int ri0 = 0, ri1 = 1;   // ring index of slot 2t, 2t+1
#pragma unroll 1
  for (int t = 0; t < 16; ++t) {
    if (t == 0) {
      asm volatile("s_waitcnt vmcnt(12)" ::: "memory");
    } else if (t == 15) {
      asm volatile("s_waitcnt vmcnt(0)" ::: "memory");
    } else {
      asm volatile("s_waitcnt vmcnt(4)" ::: "memory");
    }
    __builtin_amdgcn_s_barrier();

    if (t >= 1) {
      int s1 = 2 * t + 3;
      if (s1 <= 31) { int ia = ri1 + 2; if (ia >= 5) ia -= 5; STAGE_SLOT(s1, ia); }
      int s2 = 2 * t + 4;
      if (s2 <= 31) { int ib = ri1 + 3; if (ib >= 5) ib -= 5; STAGE_SLOT(s2, ib); }
    }

    // ---- tile body: no further syncs; waves de-sync freely ----
    const u16* sA = lds + (size_t)(wmh ? ri1 : ri0) * 16384;
    const u16* sB = lds + (size_t)(wnh ? ri1 : ri0) * 16384 + 8192;
    const u16* a0 = sA + l16 * 64 + cA;
    const u16* a1 = sA + l16 * 64 + cB;
    const u16* b0 = sB + bRow * 64 + cA;
    const u16* b1 = sB + bRow * 64 + cB;

    short8 bF[2][4];
#pragma unroll
    for (int ni = 0; ni < 4; ++ni) {
      bF[0][ni] = *(const short8*)(b0 + ni * 1024);
      bF[1][ni] = *(const short8*)(b1 + ni * 1024);
    }
    __builtin_amdgcn_s_setprio(1);
#pragma unroll
    for (int p = 0; p < 4; ++p) {
      short8 aF[2][2];
      aF[0][0] = *(const short8*)(a0 + (2 * p) * 1024);
      aF[0][1] = *(const short8*)(a1 + (2 * p) * 1024);
      aF[1][0] = *(const short8*)(a0 + (2 * p + 1) * 1024);
      aF[1][1] = *(const short8*)(a1 + (2 * p + 1) * 1024);
#pragma unroll
      for (int kh = 0; kh < 2; ++kh) {
#pragma unroll
        for (int ni = 0; ni < 4; ++ni) {
          acc[2 * p][ni]     = MFMA16(aF[0][kh], bF[kh][ni], acc[2 * p][ni]);
          acc[2 * p + 1][ni] = MFMA16(aF[1][kh], bF[kh][ni], acc[2 * p + 1][ni]);
        }
      }
    }
    __builtin_amdgcn_s_setprio(0);

    ri0 += 2; if (ri0 >= 5) ri0 -= 5;
    ri1 += 2; if (ri1 >= 5) ri1 -= 5;
  }

#pragma unroll
  for (int ni = 0; ni < 4; ++ni) {
    int col = n0 + WN + ni * 16 + l16;
    float bv = bias[col];
#pragma unroll
    for (int mi = 0; mi < 8; ++mi) {
#pragma unroll
      for (int r = 0; r < 4; ++r) {
        int row = m0 + WM + mi * 16 + quad * 4 + r;
        C[(size_t)row * EMB + col] = f2bf(acc[mi][ni][r] + bv);
      }
    }
  }
#undef STAGE_SLOT
}

// ---------------------------------------------------------------------------
// Attention: one block per (b,h).  LDS 71.7 KB -> 2 blocks/CU. (unchanged)
// ---------------------------------------------------------------------------
__global__ __launch_bounds__(256) void attn_kernel(
    const u16* __restrict__ Q, const u16* __restrict__ Kb, const u16* __restrict__ V,
    float* __restrict__ attn_out, u16* __restrict__ attended)
{
  __shared__ u16 sQK[112 * 64 * 2];
  __shared__ __align__(16) char smemB[100 * 105 * 4];
  __shared__ float sRed[256];

  u16* sQ   = sQK;
  u16* sK   = sQK + 112 * 64;
  u16* sP   = sQK;                    // overlays q+k after softmax
  float* sS = (float*)smemB;          // scores, stride 105
  u16* sVt  = (u16*)smemB;            // overlays sS after attn_out written

  const int bh = blockIdx.x;
  const int b = bh >> 4, h = bh & 15;
  const int tid = threadIdx.x;
  const int wave = tid >> 6, lane = tid & 63;
  const int quad = lane >> 4, l16 = lane & 15;
  const size_t qbase = (size_t)b * S_LEN * EMB + h * HDIM;

  // ---- preload V into registers (800 16B chunks) ----
  uint4 vr0, vr1, vr2, vr3 = make_uint4(0, 0, 0, 0);
  {
    int c0 = tid, c1 = tid + 256, c2 = tid + 512;
    vr0 = *(const uint4*)(V + qbase + (size_t)(c0 >> 3) * EMB + ((c0 & 7) << 3));
    vr1 = *(const uint4*)(V + qbase + (size_t)(c1 >> 3) * EMB + ((c1 & 7) << 3));
    vr2 = *(const uint4*)(V + qbase + (size_t)(c2 >> 3) * EMB + ((c2 & 7) << 3));
    if (tid < 32) {
      int c3 = tid + 768;
      vr3 = *(const uint4*)(V + qbase + (size_t)(c3 >> 3) * EMB + ((c3 & 7) << 3));
    }
  }

  // ---- stage q, k swizzled; zero pad rows 100..111 ----
  for (int c = tid; c < 896; c += 256) {
    int s = c >> 3, j = c & 7;
    int jg = (j ^ (s & 7)) << 3;
    uint4 qv = make_uint4(0, 0, 0, 0), kv = make_uint4(0, 0, 0, 0);
    if (s < S_LEN) {
      qv = *(const uint4*)(Q  + qbase + (size_t)s * EMB + jg);
      kv = *(const uint4*)(Kb + qbase + (size_t)s * EMB + jg);
    }
    *(uint4*)(sQ + c * 8) = qv;
    *(uint4*)(sK + c * 8) = kv;
  }
  __syncthreads();

  // ---- QK^T: 7x7 16x16 tiles, K=64, swizzled frag reads ----
  for (int t = wave; t < 49; t += 4) {
    int mi = t / 7, ni = t - mi * 7;
    f32x4 acc = {0.f, 0.f, 0.f, 0.f};
#pragma unroll
    for (int kk = 0; kk < 64; kk += 32) {
      int rq = mi * 16 + l16, rk = ni * 16 + l16;
      int cix = (kk >> 3) + quad;
      short8 a  = *(const short8*)(sQ + rq * 64 + ((cix ^ (rq & 7)) << 3));
      short8 bb = *(const short8*)(sK + rk * 64 + ((cix ^ (rk & 7)) << 3));
      acc = __builtin_amdgcn_mfma_f32_16x16x32_bf16(a, bb, acc, 0, 0, 0);
    }
    int col = ni * 16 + l16;
#pragma unroll
    for (int r = 0; r < 4; ++r) {
      int row = mi * 16 + quad * 4 + r;
      if (row < S_LEN && col < S_LEN) sS[row * 105 + col] = acc[r] * 0.125f;
    }
  }
  __syncthreads();

  // ---- zero P pad rows 100..111 (all threads) ----
  for (int i = tid; i < 192; i += 256)
    *(uint4*)(sP + (100 + (i >> 4)) * 128 + ((i & 15) << 3)) = make_uint4(0, 0, 0, 0);

  // ---- softmax: TWO threads per row; split accumulator chains ----
  if (tid < 200) {
    int row = tid >> 1, half = tid & 1;
    float* Srow = sS + row * 105;
    int c0 = half * 50, c1 = c0 + 50;
    float m0 = -1e30f, m1 = -1e30f;
    for (int c = c0; c < c1; c += 2) {
      m0 = fmaxf(m0, Srow[c]);
      m1 = fmaxf(m1, Srow[c + 1]);
    }
    sRed[tid] = fmaxf(m0, m1);
  }
  __syncthreads();
  if (tid < 200) {
    int row = tid >> 1, half = tid & 1;
    float* Srow = sS + row * 105;
    float mxv = fmaxf(sRed[row * 2], sRed[row * 2 + 1]);
    int c0 = half * 50, c1 = c0 + 50;
    float s0 = 0.f, s1 = 0.f;
    for (int c = c0; c < c1; c += 2) {
      float e0 = __expf(Srow[c] - mxv);
      float e1 = __expf(Srow[c + 1] - mxv);
      Srow[c] = e0; Srow[c + 1] = e1;
      s0 += e0; s1 += e1;
    }
    sRed[tid] = s0 + s1;
  }
  __syncthreads();
  if (tid < 200) {
    int row = tid >> 1, half = tid & 1;
    float* Srow = sS + row * 105;
    u16* Prow = sP + row * 128;
    int rs = row & 7;
    float inv = 1.f / (sRed[row * 2] + sRed[row * 2 + 1]);
    int c0 = half * 50, c1 = c0 + 50;
    for (int c = c0; c < c1; ++c) {
      float p = Srow[c] * inv;
      Srow[c] = p;
      Prow[(((c >> 3) ^ rs) << 3) + (c & 7)] = f2bf(p);
    }
    if (half == 1) {
      for (int c = S_LEN; c < 128; ++c)
        Prow[(((c >> 3) ^ rs) << 3) + (c & 7)] = 0;
    }
  }
  __syncthreads();

  // ---- coalesced attn_out write from sS ----
  {
    float* ao = attn_out + (size_t)bh * (S_LEN * S_LEN);
    for (int i = tid; i < S_LEN * S_LEN; i += 256) {
      int r = i / 100, c = i - r * 100;
      ao[i] = sS[r * 105 + c];
    }
  }
  __syncthreads();

  // ---- build V^T over the score buffer: zero, then scatter from regs ----
  for (int i = tid; i < 1024; i += 256)
    *(uint4*)(sVt + i * 8) = make_uint4(0, 0, 0, 0);
  __syncthreads();
  {
    const u16* p0 = (const u16*)&vr0;
    const u16* p1 = (const u16*)&vr1;
    const u16* p2 = (const u16*)&vr2;
    const u16* p3 = (const u16*)&vr3;
    int c0 = tid, c1 = tid + 256, c2 = tid + 512, c3 = tid + 768;
#pragma unroll
    for (int j = 0; j < 8; ++j) {
      int s, d;
      s = c0 >> 3; d = ((c0 & 7) << 3) + j;
      sVt[d * 128 + (((s >> 3) ^ (d & 7)) << 3) + (s & 7)] = p0[j];
      s = c1 >> 3; d = ((c1 & 7) << 3) + j;
      sVt[d * 128 + (((s >> 3) ^ (d & 7)) << 3) + (s & 7)] = p1[j];
      s = c2 >> 3; d = ((c2 & 7) << 3) + j;
      sVt[d * 128 + (((s >> 3) ^ (d & 7)) << 3) + (s & 7)] = p2[j];
      if (tid < 32) {
        s = c3 >> 3; d = ((c3 & 7) << 3) + j;
        sVt[d * 128 + (((s >> 3) ^ (d & 7)) << 3) + (s & 7)] = p3[j];
      }
    }
  }
  __syncthreads();

  // ---- PV: 7x4 16x16 tiles, K=128 (cols >=100 zero), swizzled frag reads ----
  for (int t = wave; t < 28; t += 4) {
    int mi = t >> 2, ni = t & 3;
    f32x4 acc = {0.f, 0.f, 0.f, 0.f};
#pragma unroll
    for (int kk = 0; kk < 128; kk += 32) {
      int rp = mi * 16 + l16, rv = ni * 16 + l16;
      int cix = (kk >> 3) + quad;
      short8 a  = *(const short8*)(sP  + rp * 128 + ((cix ^ (rp & 7)) << 3));
      short8 bb = *(const short8*)(sVt + rv * 128 + ((cix ^ (rv & 7)) << 3));
      acc = __builtin_amdgcn_mfma_f32_16x16x32_bf16(a, bb, acc, 0, 0, 0);
    }
    int col = ni * 16 + l16;
#pragma unroll
    for (int r = 0; r < 4; ++r) {
      int row = mi * 16 + quad * 4 + r;
      if (row < S_LEN)
        attended[((size_t)b * S_LEN + row) * EMB + h * HDIM + col] = f2bf(acc[r]);
    }
  }
}

// ---------------------------------------------------------------------------
extern "C" void kernel_launch(void* const* d_in, const int* in_sizes, int n_in,
                              void* d_out, int out_size, void* d_ws, size_t ws_size,
                              hipStream_t stream) {
  const float* x   = (const float*)d_in[0];
  const float* Wq  = (const float*)d_in[1];
  const float* bq  = (const float*)d_in[2];
  const float* Wk  = (const float*)d_in[3];
  const float* bk  = (const float*)d_in[4];
  const float* Wv  = (const float*)d_in[5];
  const float* bv  = (const float*)d_in[6];
  const float* Wo  = (const float*)d_in[7];
  const float* bo  = (const float*)d_in[8];
  const float* pos = (const float*)d_in[9];

  float* out  = (float*)d_out;                     // [B][E][S] f32
  float* attn = out + (size_t)BATCH * EMB * S_LEN; // [B][H][S][S] f32

  const size_t MTOT = (size_t)BATCH * S_LEN;       // 25600
  u16* ws   = (u16*)d_ws;
  u16* xT   = ws;                                  // [25600][1024] bf16
  u16* Qb   = ws + MTOT * EMB;
  u16* Kbuf = ws + 2 * MTOT * EMB;
  u16* Vb   = ws + 3 * MTOT * EMB;
  u16* WtQ  = ws + 4 * MTOT * EMB;
  u16* WtK  = WtQ + (size_t)EMB * EMB;
  u16* WtV  = WtK + (size_t)EMB * EMB;
  u16* WtO  = WtV + (size_t)EMB * EMB;
  u16* attended = xT;                              // reuse (xT dead after QKV gemm)
  u16* tmp      = Qb;                              // reuse (Q dead after attention)

  w_xpose<<<dim3(16, 16, 4), 256, 0, stream>>>(Wq, Wk, Wv, Wo, WtQ, WtK, WtV, WtO);
  xpose_pos<<<dim3(16, BATCH), 256, 0, stream>>>(x, pos, xT);
  gemm256<<<dim3(100, 4, 3), 512, 0, stream>>>(xT, WtQ, WtK, WtV, bq, bk, bv,
                                               Qb, Kbuf, Vb);
  attn_kernel<<<dim3(BATCH * NHEAD), 256, 0, stream>>>(Qb, Kbuf, Vb, attn, attended);
  gemm256<<<dim3(100, 4, 1), 512, 0, stream>>>(attended, WtO, WtO, WtO, bo, bo, bo,
                                               tmp, tmp, tmp);
  out_xpose<<<dim3(16, BATCH), 256, 0, stream>>>(tmp, out);
}